// Round 5
// baseline (256.176 us; speedup 1.0000x reference)
//
#include <hip/hip_runtime.h>

constexpr float IMG_SIZE = 448.0f;
constexpr float GSZ = 64.0f;           // IMG_SIZE / GRID_NUM
constexpr float LAMBDA_COORD = 5.0f;
constexpr float LAMBDA_NOOBJ = 0.1f;
constexpr float EPSF = 1e-12f;

#define BLOCK 256
#define TILE 256                       // cells per tile (1 cell/thread)
#define PRE_F4 (TILE * 10 / 4)         // 640 float4 of y_pre per tile
#define TRU_F4 (TILE * 5 / 4)          // 320 float4 of y_true per tile
#define TILE_F4 (PRE_F4 + TRU_F4)      // 960 float4 = 15 KB per tile
#define GRID 1280                      // 5 blocks/CU * 256 CUs
#define PART_OFF 16777216u             // float offset of partials in ws (64 MB)

// Faithful port of reference _iou (including the y1_t = cy_t + w_t/2 typo).
__device__ __forceinline__ float iou_one(const float* __restrict__ b,
                                         float tx, float ty, float tw, float th,
                                         float gj, float gi) {
    float cx_p = b[0] * GSZ + gj * GSZ;
    float cy_p = b[1] * GSZ + gi * GSZ;
    float w_p  = b[2] * IMG_SIZE;
    float h_p  = b[3] * IMG_SIZE;
    float x0p = cx_p - 0.5f * w_p, x1p = cx_p + 0.5f * w_p;
    float y0p = cy_p - 0.5f * h_p, y1p = cy_p + 0.5f * h_p;

    float cx_t = tx * GSZ + gj * GSZ;
    float cy_t = ty * GSZ + gi * GSZ;
    float w_t  = tw * IMG_SIZE;
    float h_t  = th * IMG_SIZE;
    float x0t = cx_t - 0.5f * w_t, x1t = cx_t + 0.5f * w_t;
    float y0t = cy_t - 0.5f * h_t;
    float y1t = cy_t + 0.5f * w_t;   // faithful typo: w_t, not h_t

    float ux0 = fmaxf(x0p, x0t), ux1 = fminf(x1p, x1t);
    float uy0 = fmaxf(y0p, y0t), uy1 = fminf(y1p, y1t);
    bool valid = (ux0 < ux1) && (uy0 < uy1);
    float au = (ux1 - ux0) * (uy1 - uy0);
    float ap = (x1p - x0p) * (y1p - y0p);
    float at = (x1t - x0t) * (y1t - y0t);
    float res = au / (ap + at - au + EPSF);
    return valid ? res : 0.0f;
}

// Per-cell loss contribution (unscaled; reduce kernel applies 1/B).
__device__ __forceinline__ float cell_loss(const float* __restrict__ p,
                                           const float* __restrict__ t,
                                           float gj, float gi) {
    float iou0 = iou_one(p,     t[0], t[1], t[2], t[3], gj, gi);
    float iou1 = iou_one(p + 5, t[0], t[1], t[2], t[3], gj, gi);
    bool obj = (t[4] == 1.0f);
    bool ch0 = iou0 > iou1;
    float loss;
    if (obj) {
        float cp = ch0 ? p[4] : p[9];
        float ct = ch0 ? iou0 : iou1;
        float d  = cp - ct;
        loss = d * d;
        float dx = (ch0 ? p[0] : p[5]) - t[0];
        float dy = (ch0 ? p[1] : p[6]) - t[1];
        loss += LAMBDA_COORD * (dx * dx + dy * dy);
        float wp = fmaxf(ch0 ? p[2] : p[7], EPSF);
        float hp = fmaxf(ch0 ? p[3] : p[8], EPSF);
        float wt = fmaxf(t[2], EPSF);
        float ht = fmaxf(t[3], EPSF);
        float dw = sqrtf(wp) - sqrtf(wt);
        float dh = sqrtf(hp) - sqrtf(ht);
        loss += LAMBDA_COORD * (dw * dw + dh * dh);
    } else {
        loss = LAMBDA_NOOBJ * (p[4] * p[4] + p[9] * p[9]);
    }
    return loss;
}

__device__ __forceinline__ float4 ld_chunk(const float4* __restrict__ pre4,
                                           const float4* __restrict__ tru4,
                                           int tile, int c) {
    if (c < PRE_F4) return pre4[(long long)tile * PRE_F4 + c];
    return tru4[(long long)tile * TRU_F4 + (c - PRE_F4)];
}

__device__ __forceinline__ void block_store(float local, float* dst) {
    #pragma unroll
    for (int off = 32; off > 0; off >>= 1)
        local += __shfl_down(local, off, 64);
    __shared__ float red[BLOCK / 64];
    int lane = threadIdx.x & 63, wid = threadIdx.x >> 6;
    if (lane == 0) red[wid] = local;
    __syncthreads();
    if (threadIdx.x == 0) {
        float s = 0.0f;
        #pragma unroll
        for (int w = 0; w < BLOCK / 64; ++w) s += red[w];
        *dst = s;
    }
}

// ---- V0: round-4 persistent double-buffered pipeline over a tile range ----
__global__ __launch_bounds__(BLOCK, 5)
void k_pipe(const float4* __restrict__ pre4,   // base of this range's y_pre
            const float4* __restrict__ tru4,   // base of this range's y_true
            float* __restrict__ partials,
            int tileCount, long long cellBase) {
    __shared__ float4 sbuf[2][TILE_F4];        // 2 x 15 KB
    int tid = threadIdx.x;
    float local = 0.0f;

    int tile = blockIdx.x;
    bool have = tile < tileCount;
    float4 r0, r1, r2, r3;
    if (have) {
        r0 = ld_chunk(pre4, tru4, tile, tid);
        r1 = ld_chunk(pre4, tru4, tile, tid + 256);
        r2 = ld_chunk(pre4, tru4, tile, tid + 512);
        if (tid < TILE_F4 - 768) r3 = ld_chunk(pre4, tru4, tile, tid + 768);
    }
    int cur = 0;
    while (have) {
        float4* db = sbuf[cur];
        db[tid]       = r0;
        db[tid + 256] = r1;
        db[tid + 512] = r2;
        if (tid < TILE_F4 - 768) db[tid + 768] = r3;
        __syncthreads();

        int next = tile + (int)gridDim.x;
        bool haveNext = next < tileCount;
        if (haveNext) {
            r0 = ld_chunk(pre4, tru4, next, tid);
            r1 = ld_chunk(pre4, tru4, next, tid + 256);
            r2 = ld_chunk(pre4, tru4, next, tid + 512);
            if (tid < TILE_F4 - 768) r3 = ld_chunk(pre4, tru4, next, tid + 768);
        }

        const float* sp = (const float*)db;
        const float* p  = sp + tid * 10;
        const float* tr = sp + TILE * 10 + tid * 5;
        int rc = (int)((cellBase + (long long)tile * TILE + tid) % 49);
        int gi = rc / 7;
        int gj = rc - gi * 7;
        local += cell_loss(p, tr, (float)gj, (float)gi);

        cur ^= 1;
        tile = next;
        have = haveNext;
    }
    block_store(local, &partials[blockIdx.x]);
}

// ---- V1: direct-from-global, no LDS, no barriers, grid-stride ----
__global__ __launch_bounds__(BLOCK)
void k_direct(const float* __restrict__ y_pre,
              const float* __restrict__ y_true,
              float* __restrict__ partials,
              long long lo1, long long hi1,
              long long lo2, long long hi2) {
    long long n1 = hi1 - lo1;
    long long n  = n1 + (hi2 - lo2);
    float local = 0.0f;
    for (long long i = (long long)blockIdx.x * BLOCK + threadIdx.x; i < n;
         i += (long long)gridDim.x * BLOCK) {
        long long c = (i < n1) ? (lo1 + i) : (lo2 + (i - n1));
        const float2* p2 = (const float2*)(y_pre + c * 10);   // 8B-aligned
        float pp[10];
        #pragma unroll
        for (int k = 0; k < 5; ++k) {
            float2 v = p2[k];
            pp[2 * k] = v.x; pp[2 * k + 1] = v.y;
        }
        const float* tb = y_true + c * 5;
        float tt[5];
        #pragma unroll
        for (int k = 0; k < 5; ++k) tt[k] = tb[k];
        int rc = (int)(c % 49);
        local += cell_loss(pp, tt, (float)(rc % 7), (float)(rc / 7));
    }
    block_store(local, &partials[blockIdx.x]);
}

// ---- V2: pure float4 stream copy of two segments into workspace ----
__global__ __launch_bounds__(BLOCK)
void k_copy2(const float4* __restrict__ a, float4* __restrict__ da, long long na,
             const float4* __restrict__ b, float4* __restrict__ db, long long nb) {
    long long n = na + nb;
    for (long long i = (long long)blockIdx.x * BLOCK + threadIdx.x; i < n;
         i += (long long)gridDim.x * BLOCK) {
        if (i < na) da[i] = a[i];
        else        db[i - na] = b[i - na];
    }
}

// ---- final reduce ----
__global__ __launch_bounds__(256)
void reduce_kernel(const float* __restrict__ partials,
                   float* __restrict__ out, int n, float invB) {
    int tid = threadIdx.x;
    float local = 0.0f;
    for (int i = tid; i < n; i += 256) local += partials[i];
    #pragma unroll
    for (int off = 32; off > 0; off >>= 1)
        local += __shfl_down(local, off, 64);
    __shared__ float smem[4];
    int lane = tid & 63, wid = tid >> 6;
    if (lane == 0) smem[wid] = local;
    __syncthreads();
    if (tid == 0)
        out[0] = (smem[0] + smem[1] + smem[2] + smem[3]) * invB;
}

extern "C" void kernel_launch(void* const* d_in, const int* in_sizes, int n_in,
                              void* d_out, int out_size, void* d_ws, size_t ws_size,
                              hipStream_t stream) {
    const float* y_pre  = (const float*)d_in[0];
    const float* y_true = (const float*)d_in[1];
    const float4* pre4  = (const float4*)y_pre;
    const float4* tru4  = (const float4*)y_true;
    float* out = (float*)d_out;

    long long cells = in_sizes[0] / 10;          // B * 7 * 7
    long long B     = cells / 49;
    float invB      = 1.0f / (float)B;

    long long T = cells / TILE;                  // full tiles (12544)
    long long q = T / 4;                         // tiles per quarter (3136)

    // Quarter layout (cells):
    //  A: [0, q*256)              -> k_pipe, cold          (D0)
    //  B: [q*256, 2q*256) + tail  -> k_direct              (D1)
    //  C: [2q*256, 3q*256)        -> copy to ws, k_pipe    (D2+D3)
    //  D: [3q*256, T*256)         -> k_pipe, cold          (D4)
    long long copyPreF4 = q * PRE_F4;            // float4 count of C's y_pre
    long long copyTruF4 = q * TRU_F4;
    size_t needCopyB  = (size_t)(copyPreF4 + copyTruF4) * 16;
    size_t needTotalB = (size_t)PART_OFF * 4 + (size_t)4 * GRID * 4;
    bool ablate = (ws_size >= needTotalB) && ((size_t)PART_OFF * 4 >= needCopyB)
                  && q > 0;

    float* partials = ablate ? ((float*)d_ws + PART_OFF) : (float*)d_ws;
    float4* wsPre = (float4*)d_ws;
    float4* wsTru = (float4*)d_ws + copyPreF4;

    // D0: pipeline, quarter A (cold)
    k_pipe<<<GRID, BLOCK, 0, stream>>>(pre4, tru4, partials + 0 * GRID,
                                       (int)q, 0LL);
    // D1: direct, quarter B (+ global tail cells)
    k_direct<<<GRID, BLOCK, 0, stream>>>(y_pre, y_true, partials + 1 * GRID,
                                         q * TILE, 2 * q * TILE,
                                         T * TILE, cells);
    if (ablate) {
        // D2: stream-copy quarter C's inputs into workspace
        k_copy2<<<2048, BLOCK, 0, stream>>>(pre4 + 2 * q * PRE_F4, wsPre, copyPreF4,
                                            tru4 + 2 * q * TRU_F4, wsTru, copyTruF4);
        // D3: pipeline, quarter C read from warm workspace image
        k_pipe<<<GRID, BLOCK, 0, stream>>>(wsPre, wsTru, partials + 2 * GRID,
                                           (int)q, 2 * q * TILE);
    } else {
        k_pipe<<<GRID, BLOCK, 0, stream>>>(pre4 + 2 * q * PRE_F4,
                                           tru4 + 2 * q * TRU_F4,
                                           partials + 2 * GRID,
                                           (int)q, 2 * q * TILE);
    }
    // D4: pipeline, quarter D (cold; order control vs D0)
    k_pipe<<<GRID, BLOCK, 0, stream>>>(pre4 + 3 * q * PRE_F4,
                                       tru4 + 3 * q * TRU_F4,
                                       partials + 3 * GRID,
                                       (int)(T - 3 * q), 3 * q * TILE);

    reduce_kernel<<<1, 256, 0, stream>>>(partials, out, 4 * GRID, invB);
}

// Round 6
// 229.050 us; speedup vs baseline: 1.1184x; 1.1184x over previous
//
#include <hip/hip_runtime.h>

constexpr float IMG_SIZE = 448.0f;
constexpr float GSZ = 64.0f;           // IMG_SIZE / GRID_NUM
constexpr float LAMBDA_COORD = 5.0f;
constexpr float LAMBDA_NOOBJ = 0.1f;
constexpr float EPSF = 1e-12f;

#define BLOCK 256
#define GRID 1536                      // 6 blocks/CU * 256 CUs, %8 == 0

// Faithful port of reference _iou (including the y1_t = cy_t + w_t/2 typo).
__device__ __forceinline__ float iou_one(const float* __restrict__ b,
                                         float tx, float ty, float tw, float th,
                                         float gj, float gi) {
    float cx_p = b[0] * GSZ + gj * GSZ;
    float cy_p = b[1] * GSZ + gi * GSZ;
    float w_p  = b[2] * IMG_SIZE;
    float h_p  = b[3] * IMG_SIZE;
    float x0p = cx_p - 0.5f * w_p, x1p = cx_p + 0.5f * w_p;
    float y0p = cy_p - 0.5f * h_p, y1p = cy_p + 0.5f * h_p;

    float cx_t = tx * GSZ + gj * GSZ;
    float cy_t = ty * GSZ + gi * GSZ;
    float w_t  = tw * IMG_SIZE;
    float h_t  = th * IMG_SIZE;
    float x0t = cx_t - 0.5f * w_t, x1t = cx_t + 0.5f * w_t;
    float y0t = cy_t - 0.5f * h_t;
    float y1t = cy_t + 0.5f * w_t;   // faithful typo: w_t, not h_t

    float ux0 = fmaxf(x0p, x0t), ux1 = fminf(x1p, x1t);
    float uy0 = fmaxf(y0p, y0t), uy1 = fminf(y1p, y1t);
    bool valid = (ux0 < ux1) && (uy0 < uy1);
    float au = (ux1 - ux0) * (uy1 - uy0);
    float ap = (x1p - x0p) * (y1p - y0p);
    float at = (x1t - x0t) * (y1t - y0t);
    float res = au / (ap + at - au + EPSF);
    return valid ? res : 0.0f;
}

// Per-cell loss contribution (unscaled; reduce kernel applies 1/B).
__device__ __forceinline__ float cell_loss(const float* __restrict__ p,
                                           const float* __restrict__ t,
                                           float gj, float gi) {
    float iou0 = iou_one(p,     t[0], t[1], t[2], t[3], gj, gi);
    float iou1 = iou_one(p + 5, t[0], t[1], t[2], t[3], gj, gi);
    bool obj = (t[4] == 1.0f);
    bool ch0 = iou0 > iou1;
    float loss;
    if (obj) {
        float cp = ch0 ? p[4] : p[9];
        float ct = ch0 ? iou0 : iou1;
        float d  = cp - ct;
        loss = d * d;
        float dx = (ch0 ? p[0] : p[5]) - t[0];
        float dy = (ch0 ? p[1] : p[6]) - t[1];
        loss += LAMBDA_COORD * (dx * dx + dy * dy);
        float wp = fmaxf(ch0 ? p[2] : p[7], EPSF);
        float hp = fmaxf(ch0 ? p[3] : p[8], EPSF);
        float wt = fmaxf(t[2], EPSF);
        float ht = fmaxf(t[3], EPSF);
        float dw = sqrtf(wp) - sqrtf(wt);
        float dh = sqrtf(hp) - sqrtf(ht);
        loss += LAMBDA_COORD * (dw * dw + dh * dh);
    } else {
        loss = LAMBDA_NOOBJ * (p[4] * p[4] + p[9] * p[9]);
    }
    return loss;
}

// No LDS, no barriers (round-5 ablation: staging/pipelining buys nothing;
// the wall is wave-issue packing). Each thread owns a PAIR of consecutive
// cells per iteration: 5xfloat4 (y_pre, 80B 16B-aligned) + 5xfloat2
// (y_true, 40B 8B-aligned). All indexing int32; rc carried incrementally.
__global__ __launch_bounds__(BLOCK, 6)
void yolo_loss_kernel(const float4* __restrict__ pre4,
                      const float2* __restrict__ tru2,
                      const float* __restrict__ y_pre,
                      const float* __restrict__ y_true,
                      float* __restrict__ partials,
                      int npairs, int cells, int rcStep) {
    int tid  = threadIdx.x;
    int gtid = blockIdx.x * BLOCK + tid;
    int stride = (int)gridDim.x * BLOCK;

    float local = 0.0f;
    int rc = (2 * gtid) % 49;              // one 32-bit mod at entry

    for (int i = gtid; i < npairs; i += stride) {
        float4 a0 = pre4[i * 5 + 0];
        float4 a1 = pre4[i * 5 + 1];
        float4 a2 = pre4[i * 5 + 2];
        float4 a3 = pre4[i * 5 + 3];
        float4 a4 = pre4[i * 5 + 4];
        float2 b0 = tru2[i * 5 + 0];
        float2 b1 = tru2[i * 5 + 1];
        float2 b2 = tru2[i * 5 + 2];
        float2 b3 = tru2[i * 5 + 3];
        float2 b4 = tru2[i * 5 + 4];

        float p0[10] = {a0.x, a0.y, a0.z, a0.w, a1.x,
                        a1.y, a1.z, a1.w, a2.x, a2.y};
        float t0[5]  = {b0.x, b0.y, b1.x, b1.y, b2.x};
        float p1[10] = {a2.z, a2.w, a3.x, a3.y, a3.z,
                        a3.w, a4.x, a4.y, a4.z, a4.w};
        float t1[5]  = {b2.y, b3.x, b3.y, b4.x, b4.y};

        int g0 = rc / 7;
        int j0 = rc - 7 * g0;
        local += cell_loss(p0, t0, (float)j0, (float)g0);

        int r1 = rc + 1; if (r1 == 49) r1 = 0;
        int g1 = r1 / 7;
        int j1 = r1 - 7 * g1;
        local += cell_loss(p1, t1, (float)j1, (float)g1);

        rc += rcStep; if (rc >= 49) rc -= 49;   // rcStep = (2*stride) % 49
    }

    // Odd-cell tail (cells % 2 != 0) — not hit for B=65536, kept for safety.
    if (gtid == 0 && (cells & 1)) {
        int c = cells - 1;
        int rcl = c % 49;
        local += cell_loss(y_pre + (size_t)c * 10, y_true + (size_t)c * 5,
                           (float)(rcl % 7), (float)(rcl / 7));
    }

    // Wave-64 shuffle reduce; one plain store per block.
    #pragma unroll
    for (int off = 32; off > 0; off >>= 1)
        local += __shfl_down(local, off, 64);

    __shared__ float red[BLOCK / 64];
    int lane = tid & 63, wid = tid >> 6;
    if (lane == 0) red[wid] = local;
    __syncthreads();
    if (tid == 0) {
        float s = 0.0f;
        #pragma unroll
        for (int w = 0; w < BLOCK / 64; ++w) s += red[w];
        partials[blockIdx.x] = s;
    }
}

// One block reduces the per-block partials and writes the final scaled loss.
__global__ __launch_bounds__(256)
void reduce_kernel(const float* __restrict__ partials,
                   float* __restrict__ out, int n, float invB) {
    int tid = threadIdx.x;
    float local = 0.0f;
    for (int i = tid; i < n; i += 256) local += partials[i];
    #pragma unroll
    for (int off = 32; off > 0; off >>= 1)
        local += __shfl_down(local, off, 64);
    __shared__ float smem[4];
    int lane = tid & 63, wid = tid >> 6;
    if (lane == 0) smem[wid] = local;
    __syncthreads();
    if (tid == 0)
        out[0] = (smem[0] + smem[1] + smem[2] + smem[3]) * invB;
}

extern "C" void kernel_launch(void* const* d_in, const int* in_sizes, int n_in,
                              void* d_out, int out_size, void* d_ws, size_t ws_size,
                              hipStream_t stream) {
    const float* y_pre  = (const float*)d_in[0];
    const float* y_true = (const float*)d_in[1];
    float* out = (float*)d_out;
    float* partials = (float*)d_ws;

    int cells  = in_sizes[0] / 10;          // B * 7 * 7
    int B      = cells / 49;
    float invB = 1.0f / (float)B;
    int npairs = cells / 2;                 // 1,605,632 for B=65536

    int blocks = GRID;
    int maxb = (npairs + BLOCK - 1) / BLOCK;
    if (blocks > maxb) blocks = maxb;
    if (blocks < 1) blocks = 1;
    int rcStep = (int)((2LL * blocks * BLOCK) % 49);

    yolo_loss_kernel<<<blocks, BLOCK, 0, stream>>>(
        (const float4*)y_pre, (const float2*)y_true,
        y_pre, y_true, partials, npairs, cells, rcStep);
    reduce_kernel<<<1, 256, 0, stream>>>(partials, out, blocks, invB);
}